// Round 3
// baseline (156.981 us; speedup 1.0000x reference)
//
#include <hip/hip_runtime.h>
#include <hip/hip_bf16.h>
#include <cstdint>
#include <cstddef>

#define B_SZ   2
#define T_CTX  2048
#define DIM_C  1024
#define NHEAD  16
#define HD     64
#define NBH    (B_SZ*NHEAD)

typedef __attribute__((ext_vector_type(8))) short short8;
typedef __attribute__((ext_vector_type(4))) float f32x4;

union BV8 { short8 s; __hip_bfloat16 h[8]; unsigned short u[8]; };
union U32x4 { uint32_t u[4]; short8 s8; };

#define GLD16(gp, lp) \
  __builtin_amdgcn_global_load_lds((const __attribute__((address_space(1))) void*)(gp), \
                                   (__attribute__((address_space(3))) void*)(lp), 16, 0, 0)

__device__ inline uint32_t pkbf(float a, float b) {
  union { __hip_bfloat16 h; unsigned short u; } ua, ub;
  ua.h = __float2bfloat16(a);
  ub.h = __float2bfloat16(b);
  return ((uint32_t)ub.u << 16) | (uint32_t)ua.u;
}

// ---------------- fp32 -> bf16 convert ----------------
__global__ __launch_bounds__(256) void cvt_f32_bf16(const float* __restrict__ in,
                                                    __hip_bfloat16* __restrict__ out,
                                                    int n4) {
  int i = blockIdx.x * 256 + threadIdx.x;
  if (i >= n4) return;
  float4 v = reinterpret_cast<const float4*>(in)[i];
  BV8 o;
  o.h[0] = __float2bfloat16(v.x);
  o.h[1] = __float2bfloat16(v.y);
  o.h[2] = __float2bfloat16(v.z);
  o.h[3] = __float2bfloat16(v.w);
  ushort4 st = { o.u[0], o.u[1], o.u[2], o.u[3] };
  reinterpret_cast<ushort4*>(out)[i] = st;
}

// ---------------- bf16 GEMM, C = A[M,K] * Bt[N,K]^T ----------------
template <typename OutT>
__global__ __launch_bounds__(256) void gemm_bt(const __hip_bfloat16* __restrict__ A,
                                               const __hip_bfloat16* __restrict__ Bt,
                                               OutT* __restrict__ C,
                                               int M, int N, int K) {
  __shared__ __align__(16) __hip_bfloat16 As[128 * 32];
  __shared__ __align__(16) __hip_bfloat16 Bs[128 * 32];
  const int tid = threadIdx.x;
  const int w = tid >> 6, l = tid & 63;
  const int l15 = l & 15, l4 = l >> 4;
  const int wr = w >> 1, wc = w & 1;
  const long bm = (long)blockIdx.y * 128;
  const long bn = (long)blockIdx.x * 128;

  f32x4 acc[4][4] = {};

  const int srow = tid >> 2;
  const int scol = (tid & 3) * 16;
  char* AsB = (char*)As;
  char* BsB = (char*)Bs;
  const char* Ab  = (const char*)A;
  const char* Btb = (const char*)Bt;

  for (int kt = 0; kt < K; kt += 32) {
    __syncthreads();
#pragma unroll
    for (int it = 0; it < 2; ++it) {
      long arow = bm + it * 64 + srow;
      GLD16(Ab + (arow * K + kt) * 2 + scol, AsB + it * 4096 + w * 1024);
      long brow = bn + it * 64 + srow;
      GLD16(Btb + (brow * K + kt) * 2 + scol, BsB + it * 4096 + w * 1024);
    }
    __syncthreads();
    short8 aF[4], bF[4];
#pragma unroll
    for (int m = 0; m < 4; ++m)
      aF[m] = *(const short8*)(AsB + (wr * 64 + m * 16 + l15) * 64 + l4 * 16);
#pragma unroll
    for (int n = 0; n < 4; ++n)
      bF[n] = *(const short8*)(BsB + (wc * 64 + n * 16 + l15) * 64 + l4 * 16);
#pragma unroll
    for (int m = 0; m < 4; ++m)
#pragma unroll
      for (int n = 0; n < 4; ++n)
        acc[m][n] = __builtin_amdgcn_mfma_f32_16x16x32_bf16(aF[m], bF[n], acc[m][n], 0, 0, 0);
  }

#pragma unroll
  for (int m = 0; m < 4; ++m)
#pragma unroll
    for (int n = 0; n < 4; ++n)
#pragma unroll
      for (int r = 0; r < 4; ++r) {
        long row = bm + wr * 64 + m * 16 + l4 * 4 + r;
        long col = bn + wc * 64 + n * 16 + l15;
        float v = acc[m][n][r];
        if constexpr (sizeof(OutT) == 2) {
          C[row * N + col] = __float2bfloat16(v);
        } else {
          C[row * N + col] = v;
        }
      }
}

// ---------------- RoPE + repack ----------------
// Q scale folds softmax 1/8 AND log2(e) so attention softmax can use exp2 natively.
__global__ __launch_bounds__(256) void rope_pack(const __hip_bfloat16* __restrict__ qkv,
                                                 __hip_bfloat16* __restrict__ Qb,
                                                 __hip_bfloat16* __restrict__ Kb,
                                                 __hip_bfloat16* __restrict__ VTb) {
  __shared__ __hip_bfloat16 vt[64][72];
  const int bh = blockIdx.x;
  const int b = bh >> 4, h = bh & 15;
  const int t0 = blockIdx.y * 64;
  const int tid = threadIdx.x;
  const float QSCL = 0.125f * 1.4426950408889634f;

#pragma unroll
  for (int rep = 0; rep < 2; ++rep) {
    int idx = rep * 256 + tid;
    int tt = idx >> 3;
    int d0 = (idx & 7) * 8;
    int t = t0 + tt;
    size_t src = ((size_t)(b * T_CTX + t)) * 3072 + h * 64 + d0;
    BV8 qv, kv, vv, qo, ko;
    qv.s = *(const short8*)(qkv + src);
    kv.s = *(const short8*)(qkv + src + 1024);
    vv.s = *(const short8*)(qkv + src + 2048);
#pragma unroll
    for (int p = 0; p < 4; ++p) {
      int i = (d0 >> 1) + p;
      float inv = exp2f(-13.287712379549449f * ((float)(2 * i) * (1.0f / 64.0f)));
      float ang = (float)t * inv;
      float sn, cn;
      sincosf(ang, &sn, &cn);
      float q1 = __bfloat162float(qv.h[2 * p]);
      float q2 = __bfloat162float(qv.h[2 * p + 1]);
      float k1 = __bfloat162float(kv.h[2 * p]);
      float k2 = __bfloat162float(kv.h[2 * p + 1]);
      qo.h[2 * p]     = __float2bfloat16((q1 * cn - q2 * sn) * QSCL);
      qo.h[2 * p + 1] = __float2bfloat16((q1 * sn + q2 * cn) * QSCL);
      ko.h[2 * p]     = __float2bfloat16(k1 * cn - k2 * sn);
      ko.h[2 * p + 1] = __float2bfloat16(k1 * sn + k2 * cn);
    }
    size_t dst = ((size_t)bh * T_CTX + t) * 64 + d0;
    *(short8*)(Qb + dst) = qo.s;
    *(short8*)(Kb + dst) = ko.s;
#pragma unroll
    for (int j = 0; j < 8; ++j) vt[d0 + j][tt] = vv.h[j];
  }
  __syncthreads();
#pragma unroll
  for (int rep = 0; rep < 2; ++rep) {
    int idx = rep * 256 + tid;
    int d = idx >> 3;
    int toff = (idx & 7) * 8;
    BV8 o;
#pragma unroll
    for (int j = 0; j < 8; ++j) o.h[j] = vt[d][toff + j];
    *(short8*)(VTb + ((size_t)bh * 64 + d) * T_CTX + t0 + toff) = o.s;
  }
}

// ---------------- flash attention, K-split (flash-decoding) ----------------
// Block = (bh, q-block of 128 rows, k-chunk of 512). 4 waves x 32 q-rows.
// Swapped QK^T (S^T = mfma(K, Q^T)): reduction axis lane-local.
// nc==1 chunks write Y directly; else normalized partial O (bf16) + LSE.
__global__ __launch_bounds__(256) void flash_attn(const __hip_bfloat16* __restrict__ Qb,
                                                  const __hip_bfloat16* __restrict__ Kb,
                                                  const __hip_bfloat16* __restrict__ VTb,
                                                  __hip_bfloat16* __restrict__ Y,
                                                  __hip_bfloat16* __restrict__ Opart,
                                                  float* __restrict__ LSE) {
  __shared__ __align__(16) char smem[32768];
  const int bh = blockIdx.x;
  const int b = bh >> 4, h = bh & 15;
  // decode blockIdx.y -> (qi, c); nc(qi) = (qi>>2)+1, chunk = 512 k-cols = 8 tiles
  int yid = blockIdx.y, qi = 0;
  for (;;) {
    int ncq = (qi >> 2) + 1;
    if (yid < ncq) break;
    yid -= ncq;
    ++qi;
  }
  const int c = yid;
  const int nc = (qi >> 2) + 1;
  const int q0 = qi * 128;
  const int t0tile = c * 8;
  const int t1tile = min(t0tile + 8, (q0 + 128) >> 6);

  const int tid = threadIdx.x;
  const int w = tid >> 6, l = tid & 63;
  const int l15 = l & 15, g = l >> 4;
  const int gh = g >> 1;
  const int srcA = l15 + ((g & 1) << 5);
  const int srcB = srcA + 16;
  const int qw = q0 + w * 32;

  // Q as B-operand fragments: B[d][q], q = l15, d = s*32 + g*8 + j
  short8 qB[2][2];
#pragma unroll
  for (int qt = 0; qt < 2; ++qt)
#pragma unroll
    for (int s = 0; s < 2; ++s)
      qB[qt][s] = *(const short8*)(Qb + ((size_t)bh * T_CTX + qw + qt * 16 + l15) * 64 +
                                   s * 32 + g * 8);

  f32x4 o[4][2] = {};  // O^T[dt][qt]: col=q=l15, row=d=g*4+r
  float mrow[2] = { -1e30f, -1e30f };
  float lrow[2] = { 0.0f, 0.0f };

  const int rowb = w * 8 + (l >> 3);
  const int colS = (l & 7) * 16;

  // prologue: stage tile t0tile into buffer 0
  {
    const int kv0 = t0tile << 6;
#pragma unroll
    for (int rnd = 0; rnd < 2; ++rnd) {
      int row = rnd * 32 + rowb;
      int sw = colS ^ ((row & 7) << 4);
      GLD16((const char*)Kb + (((size_t)bh * T_CTX + kv0 + row) << 7) + sw,
            smem + rnd * 4096 + w * 1024);
      GLD16((const char*)VTb + ((((size_t)bh * 64 + row) * T_CTX + kv0) << 1) + sw,
            smem + 8192 + rnd * 4096 + w * 1024);
    }
  }

  int cur = 0;
  for (int t = t0tile; t < t1tile; ++t) {
    const int kv0 = t << 6;
    __syncthreads();  // buf[cur] ready
    if (t + 1 < t1tile) {
      const int nkv0 = (t + 1) << 6;
#pragma unroll
      for (int rnd = 0; rnd < 2; ++rnd) {
        int row = rnd * 32 + rowb;
        int sw = colS ^ ((row & 7) << 4);
        GLD16((const char*)Kb + (((size_t)bh * T_CTX + nkv0 + row) << 7) + sw,
              smem + (cur ^ 1) * 16384 + rnd * 4096 + w * 1024);
        GLD16((const char*)VTb + ((((size_t)bh * 64 + row) * T_CTX + nkv0) << 1) + sw,
              smem + (cur ^ 1) * 16384 + 8192 + rnd * 4096 + w * 1024);
      }
    }
    if (kv0 <= qw + 31) {
      const char* KsB = smem + cur * 16384;
      const char* VsB = KsB + 8192;

      // QK^T (swapped): sT[kt][qt], k = kv0 + kt*16 + g*4 + r, q = qw + qt*16 + l15
      f32x4 sT[4][2] = {};
#pragma unroll
      for (int s = 0; s < 2; ++s) {
        short8 kA[4];
#pragma unroll
        for (int kt = 0; kt < 4; ++kt) {
          int R = kt * 16 + l15;
          kA[kt] = *(const short8*)(KsB + R * 128 + ((s * 64 + g * 16) ^ ((R & 7) << 4)));
        }
        __builtin_amdgcn_s_setprio(1);
#pragma unroll
        for (int kt = 0; kt < 4; ++kt)
#pragma unroll
          for (int qt = 0; qt < 2; ++qt)
            sT[kt][qt] = __builtin_amdgcn_mfma_f32_16x16x32_bf16(kA[kt], qB[qt][s], sT[kt][qt], 0, 0, 0);
        __builtin_amdgcn_s_setprio(0);
      }

      if (kv0 + 63 > qw) {  // diagonal region: causal mask
#pragma unroll
        for (int kt = 0; kt < 4; ++kt) {
          int kg = kv0 + kt * 16 + g * 4;
#pragma unroll
          for (int qt = 0; qt < 2; ++qt) {
            int qg = qw + qt * 16 + l15;
#pragma unroll
            for (int r = 0; r < 4; ++r)
              if (kg + r > qg) sT[kt][qt][r] = -1e30f;
          }
        }
      }

      // hoist V fragment reads: LDS latency overlaps the softmax VALU chain
      short8 vA[2][4];
#pragma unroll
      for (int s = 0; s < 2; ++s)
#pragma unroll
        for (int dt = 0; dt < 4; ++dt) {
          int R = dt * 16 + l15;
          vA[s][dt] = *(const short8*)(VsB + R * 128 + ((s * 64 + g * 16) ^ ((R & 7) << 4)));
        }

      // online softmax in exp2 domain (log2e folded into Q scale)
      short8 pB[2][2];
#pragma unroll
      for (int qt = 0; qt < 2; ++qt) {
        float mx = sT[0][qt][0];
#pragma unroll
        for (int kt = 0; kt < 4; ++kt)
#pragma unroll
          for (int r = 0; r < 4; ++r) mx = fmaxf(mx, sT[kt][qt][r]);
        mx = fmaxf(mx, __shfl_xor(mx, 16));
        mx = fmaxf(mx, __shfl_xor(mx, 32));
        float mnew = fmaxf(mrow[qt], mx);
        float fac = exp2f(mrow[qt] - mnew);
        mrow[qt] = mnew;
        float ps = 0.0f;
        uint32_t W[4][2];
#pragma unroll
        for (int kt = 0; kt < 4; ++kt) {
          float p0 = exp2f(sT[kt][qt][0] - mnew);
          float p1 = exp2f(sT[kt][qt][1] - mnew);
          float p2 = exp2f(sT[kt][qt][2] - mnew);
          float p3 = exp2f(sT[kt][qt][3] - mnew);
          ps += (p0 + p1) + (p2 + p3);
          W[kt][0] = pkbf(p0, p1);
          W[kt][1] = pkbf(p2, p3);
        }
        ps += __shfl_xor(ps, 16);
        ps += __shfl_xor(ps, 32);
        lrow[qt] = lrow[qt] * fac + ps;
#pragma unroll
        for (int dt = 0; dt < 4; ++dt)
#pragma unroll
          for (int r = 0; r < 4; ++r) o[dt][qt][r] *= fac;
        // repack P^T acc-layout -> B-frag (k = s*32 + g*8 + j) via lane gathers
#pragma unroll
        for (int s = 0; s < 2; ++s) {
          uint32_t a0 = (uint32_t)__shfl((int)W[2 * s][0], srcA);
          uint32_t a1 = (uint32_t)__shfl((int)W[2 * s][1], srcA);
          uint32_t b0 = (uint32_t)__shfl((int)W[2 * s + 1][0], srcA);
          uint32_t b1 = (uint32_t)__shfl((int)W[2 * s + 1][1], srcA);
          uint32_t c0 = (uint32_t)__shfl((int)W[2 * s][0], srcB);
          uint32_t c1 = (uint32_t)__shfl((int)W[2 * s][1], srcB);
          uint32_t d0 = (uint32_t)__shfl((int)W[2 * s + 1][0], srcB);
          uint32_t d1 = (uint32_t)__shfl((int)W[2 * s + 1][1], srcB);
          U32x4 u;
          u.u[0] = gh ? b0 : a0;
          u.u[1] = gh ? b1 : a1;
          u.u[2] = gh ? d0 : c0;
          u.u[3] = gh ? d1 : c1;
          pB[qt][s] = u.s8;
        }
      }

      // PV: O^T[dt][qt] += mfma(A=V^T, B=P^T)
      __builtin_amdgcn_s_setprio(1);
#pragma unroll
      for (int s = 0; s < 2; ++s)
#pragma unroll
        for (int dt = 0; dt < 4; ++dt)
#pragma unroll
          for (int qt = 0; qt < 2; ++qt)
            o[dt][qt] = __builtin_amdgcn_mfma_f32_16x16x32_bf16(vA[s][dt], pB[qt][s], o[dt][qt], 0, 0, 0);
      __builtin_amdgcn_s_setprio(0);
    }
    cur ^= 1;
  }

  if (nc == 1) {
    // single chunk: final output
#pragma unroll
    for (int qt = 0; qt < 2; ++qt) {
      float inv = 1.0f / lrow[qt];
      size_t rowoff = ((size_t)(b * T_CTX + qw + qt * 16 + l15)) * DIM_C + h * 64;
#pragma unroll
      for (int dt = 0; dt < 4; ++dt) {
        union { ushort4 v; unsigned short us[4]; } st;
#pragma unroll
        for (int r = 0; r < 4; ++r) {
          union { __hip_bfloat16 h; unsigned short u; } cv;
          cv.h = __float2bfloat16(o[dt][qt][r] * inv);
          st.us[r] = cv.u;
        }
        *(ushort4*)(Y + rowoff + dt * 16 + g * 4) = st.v;
      }
    }
  } else {
    // partial: write normalized O (bf16) + LSE (log2 domain)
    const int slot = (int)blockIdx.y - 4;  // y ordering == slot ordering for qi>=4
    const size_t base = ((size_t)(bh * 36 + slot)) * 8192;
#pragma unroll
    for (int qt = 0; qt < 2; ++qt) {
      float inv = 1.0f / lrow[qt];
      int rl = w * 32 + qt * 16 + l15;
      size_t rowoff = base + (size_t)rl * 64;
#pragma unroll
      for (int dt = 0; dt < 4; ++dt) {
        union { ushort4 v; unsigned short us[4]; } st;
#pragma unroll
        for (int r = 0; r < 4; ++r) {
          union { __hip_bfloat16 h; unsigned short u; } cv;
          cv.h = __float2bfloat16(o[dt][qt][r] * inv);
          st.us[r] = cv.u;
        }
        *(ushort4*)(Opart + rowoff + dt * 16 + g * 4) = st.v;
      }
      if (g == 0) LSE[(size_t)(bh * 36 + slot) * 128 + rl] = mrow[qt] + log2f(lrow[qt]);
    }
  }
}

// ---------------- combine partial attention outputs ----------------
// grid (NBH, 12): qi = 4 + blockIdx.y. 256 threads: 128 rows x 2 d-halves.
__global__ __launch_bounds__(256) void attn_combine(const __hip_bfloat16* __restrict__ Opart,
                                                    const float* __restrict__ LSE,
                                                    __hip_bfloat16* __restrict__ Y) {
  const int bh = blockIdx.x;
  const int qi = 4 + blockIdx.y;
  const int nc = (qi >> 2) + 1;
  int slotbase = 0;
  for (int j = 4; j < qi; ++j) slotbase += (j >> 2) + 1;
  const int b = bh >> 4, h = bh & 15;
  const int tid = threadIdx.x;
  const int row = tid >> 1;
  const int d0 = (tid & 1) * 32;

  float lse[4];
  float M = -1e30f;
  for (int c = 0; c < nc; ++c) {
    lse[c] = LSE[(size_t)(bh * 36 + slotbase + c) * 128 + row];
    M = fmaxf(M, lse[c]);
  }
  float wsum = 0.0f;
  float acc[32] = {};
  for (int c = 0; c < nc; ++c) {
    float wc = exp2f(lse[c] - M);
    wsum += wc;
    const __hip_bfloat16* src = Opart + ((size_t)(bh * 36 + slotbase + c)) * 8192 + row * 64 + d0;
#pragma unroll
    for (int v = 0; v < 4; ++v) {
      BV8 vv;
      vv.s = *(const short8*)(src + v * 8);
#pragma unroll
      for (int j = 0; j < 8; ++j) acc[v * 8 + j] += wc * __bfloat162float(vv.h[j]);
    }
  }
  float inv = 1.0f / wsum;
  size_t dst = ((size_t)(b * T_CTX + qi * 128 + row)) * DIM_C + h * 64 + d0;
#pragma unroll
  for (int v = 0; v < 4; ++v) {
    BV8 ob;
#pragma unroll
    for (int j = 0; j < 8; ++j) ob.h[j] = __float2bfloat16(acc[v * 8 + j] * inv);
    *(short8*)(Y + dst + v * 8) = ob.s;
  }
}

// ---------------- launcher ----------------
extern "C" void kernel_launch(void* const* d_in, const int* in_sizes, int n_in,
                              void* d_out, int out_size, void* d_ws, size_t ws_size,
                              hipStream_t stream) {
  const float* x     = (const float*)d_in[0];
  const float* qkv_w = (const float*)d_in[1];
  const float* out_w = (const float*)d_in[2];
  float* out = (float*)d_out;

  char* ws = (char*)d_ws;
  const size_t MB = 1024 * 1024;
  __hip_bfloat16* xb    = (__hip_bfloat16*)(ws + 0 * MB);
  __hip_bfloat16* wqkvb = (__hip_bfloat16*)(ws + 8 * MB);
  __hip_bfloat16* woutb = (__hip_bfloat16*)(ws + 14 * MB);
  __hip_bfloat16* qkvb  = (__hip_bfloat16*)(ws + 16 * MB);  // dead after rope_pack
  __hip_bfloat16* Opart = (__hip_bfloat16*)(ws + 16 * MB);  // 32*36*8192*2B = 18.9MB
  float*          LSE   = (float*)(ws + 35 * MB);           // 32*36*128*4B = 0.6MB
  __hip_bfloat16* Qb    = (__hip_bfloat16*)(ws + 40 * MB);
  __hip_bfloat16* Kb    = (__hip_bfloat16*)(ws + 48 * MB);
  __hip_bfloat16* VTb   = (__hip_bfloat16*)(ws + 56 * MB);
  __hip_bfloat16* yb    = (__hip_bfloat16*)(ws + 64 * MB);

  cvt_f32_bf16<<<4096, 256, 0, stream>>>(x, xb, 1048576);
  cvt_f32_bf16<<<3072, 256, 0, stream>>>(qkv_w, wqkvb, 786432);
  cvt_f32_bf16<<<1024, 256, 0, stream>>>(out_w, woutb, 262144);

  gemm_bt<__hip_bfloat16><<<dim3(24, 32), 256, 0, stream>>>(xb, wqkvb, qkvb, 4096, 3072, 1024);

  rope_pack<<<dim3(32, 32), 256, 0, stream>>>(qkvb, Qb, Kb, VTb);

  // K-split flash attention: Sum_qi nc(qi) = 40 y-slots
  flash_attn<<<dim3(NBH, 40), 256, 0, stream>>>(Qb, Kb, VTb, yb, Opart, LSE);

  attn_combine<<<dim3(NBH, 12), 256, 0, stream>>>(Opart, LSE, yb);

  gemm_bt<float><<<dim3(8, 32), 256, 0, stream>>>(yb, woutb, out, 4096, 1024, 1024);
}

// Round 5
// 140.915 us; speedup vs baseline: 1.1140x; 1.1140x over previous
//
#include <hip/hip_runtime.h>
#include <hip/hip_bf16.h>
#include <cstdint>
#include <cstddef>

#define B_SZ   2
#define T_CTX  2048
#define DIM_C  1024
#define NHEAD  16
#define HD     64
#define NBH    (B_SZ*NHEAD)

typedef __attribute__((ext_vector_type(8))) short short8;
typedef __attribute__((ext_vector_type(4))) float f32x4;
typedef __attribute__((ext_vector_type(16))) float f32x16;

union BV8 { short8 s; __hip_bfloat16 h[8]; unsigned short u[8]; };
union U32x4 { uint32_t u[4]; short8 s8; };

#define GLD16(gp, lp) \
  __builtin_amdgcn_global_load_lds((const __attribute__((address_space(1))) void*)(gp), \
                                   (__attribute__((address_space(3))) void*)(lp), 16, 0, 0)

// pack two f32 -> bf16 pair (lo = first arg), pure IR (hazard-safe feed into MFMA)
__device__ inline uint32_t pkbf(float a, float b) {
  union { __hip_bfloat16 h; unsigned short u; } ua, ub;
  ua.h = __float2bfloat16(a);
  ub.h = __float2bfloat16(b);
  return ((uint32_t)ub.u << 16) | (uint32_t)ua.u;
}

// ---------------- fp32 -> bf16 convert ----------------
__global__ __launch_bounds__(256) void cvt_f32_bf16(const float* __restrict__ in,
                                                    __hip_bfloat16* __restrict__ out,
                                                    int n4) {
  int i = blockIdx.x * 256 + threadIdx.x;
  if (i >= n4) return;
  float4 v = reinterpret_cast<const float4*>(in)[i];
  BV8 o;
  o.h[0] = __float2bfloat16(v.x);
  o.h[1] = __float2bfloat16(v.y);
  o.h[2] = __float2bfloat16(v.z);
  o.h[3] = __float2bfloat16(v.w);
  ushort4 st = { o.u[0], o.u[1], o.u[2], o.u[3] };
  reinterpret_cast<ushort4*>(out)[i] = st;
}

// ---------------- bf16 GEMM, C = A[M,K] * Bt[N,K]^T ----------------
template <typename OutT>
__global__ __launch_bounds__(256) void gemm_bt(const __hip_bfloat16* __restrict__ A,
                                               const __hip_bfloat16* __restrict__ Bt,
                                               OutT* __restrict__ C,
                                               int M, int N, int K) {
  __shared__ __align__(16) __hip_bfloat16 As[128 * 32];
  __shared__ __align__(16) __hip_bfloat16 Bs[128 * 32];
  const int tid = threadIdx.x;
  const int w = tid >> 6, l = tid & 63;
  const int l15 = l & 15, l4 = l >> 4;
  const int wr = w >> 1, wc = w & 1;
  const long bm = (long)blockIdx.y * 128;
  const long bn = (long)blockIdx.x * 128;

  f32x4 acc[4][4] = {};

  const int srow = tid >> 2;
  const int scol = (tid & 3) * 16;
  char* AsB = (char*)As;
  char* BsB = (char*)Bs;
  const char* Ab  = (const char*)A;
  const char* Btb = (const char*)Bt;

  for (int kt = 0; kt < K; kt += 32) {
    __syncthreads();
#pragma unroll
    for (int it = 0; it < 2; ++it) {
      long arow = bm + it * 64 + srow;
      GLD16(Ab + (arow * K + kt) * 2 + scol, AsB + it * 4096 + w * 1024);
      long brow = bn + it * 64 + srow;
      GLD16(Btb + (brow * K + kt) * 2 + scol, BsB + it * 4096 + w * 1024);
    }
    __syncthreads();
    short8 aF[4], bF[4];
#pragma unroll
    for (int m = 0; m < 4; ++m)
      aF[m] = *(const short8*)(AsB + (wr * 64 + m * 16 + l15) * 64 + l4 * 16);
#pragma unroll
    for (int n = 0; n < 4; ++n)
      bF[n] = *(const short8*)(BsB + (wc * 64 + n * 16 + l15) * 64 + l4 * 16);
#pragma unroll
    for (int m = 0; m < 4; ++m)
#pragma unroll
      for (int n = 0; n < 4; ++n)
        acc[m][n] = __builtin_amdgcn_mfma_f32_16x16x32_bf16(aF[m], bF[n], acc[m][n], 0, 0, 0);
  }

#pragma unroll
  for (int m = 0; m < 4; ++m)
#pragma unroll
    for (int n = 0; n < 4; ++n)
#pragma unroll
      for (int r = 0; r < 4; ++r) {
        long row = bm + wr * 64 + m * 16 + l4 * 4 + r;
        long col = bn + wc * 64 + n * 16 + l15;
        float v = acc[m][n][r];
        if constexpr (sizeof(OutT) == 2) {
          C[row * N + col] = __float2bfloat16(v);
        } else {
          C[row * N + col] = v;
        }
      }
}

// ---------------- RoPE + repack ----------------
// Q scale folds softmax 1/8 AND log2(e) so attention softmax can use exp2 natively.
__global__ __launch_bounds__(256) void rope_pack(const __hip_bfloat16* __restrict__ qkv,
                                                 __hip_bfloat16* __restrict__ Qb,
                                                 __hip_bfloat16* __restrict__ Kb,
                                                 __hip_bfloat16* __restrict__ VTb) {
  __shared__ __hip_bfloat16 vt[64][72];
  const int bh = blockIdx.x;
  const int b = bh >> 4, h = bh & 15;
  const int t0 = blockIdx.y * 64;
  const int tid = threadIdx.x;
  const float QSCL = 0.125f * 1.4426950408889634f;

#pragma unroll
  for (int rep = 0; rep < 2; ++rep) {
    int idx = rep * 256 + tid;
    int tt = idx >> 3;
    int d0 = (idx & 7) * 8;
    int t = t0 + tt;
    size_t src = ((size_t)(b * T_CTX + t)) * 3072 + h * 64 + d0;
    BV8 qv, kv, vv, qo, ko;
    qv.s = *(const short8*)(qkv + src);
    kv.s = *(const short8*)(qkv + src + 1024);
    vv.s = *(const short8*)(qkv + src + 2048);
#pragma unroll
    for (int p = 0; p < 4; ++p) {
      int i = (d0 >> 1) + p;
      float inv = exp2f(-13.287712379549449f * ((float)(2 * i) * (1.0f / 64.0f)));
      float ang = (float)t * inv;
      float sn, cn;
      sincosf(ang, &sn, &cn);
      float q1 = __bfloat162float(qv.h[2 * p]);
      float q2 = __bfloat162float(qv.h[2 * p + 1]);
      float k1 = __bfloat162float(kv.h[2 * p]);
      float k2 = __bfloat162float(kv.h[2 * p + 1]);
      qo.h[2 * p]     = __float2bfloat16((q1 * cn - q2 * sn) * QSCL);
      qo.h[2 * p + 1] = __float2bfloat16((q1 * sn + q2 * cn) * QSCL);
      ko.h[2 * p]     = __float2bfloat16(k1 * cn - k2 * sn);
      ko.h[2 * p + 1] = __float2bfloat16(k1 * sn + k2 * cn);
    }
    size_t dst = ((size_t)bh * T_CTX + t) * 64 + d0;
    *(short8*)(Qb + dst) = qo.s;
    *(short8*)(Kb + dst) = ko.s;
#pragma unroll
    for (int j = 0; j < 8; ++j) vt[d0 + j][tt] = vv.h[j];
  }
  __syncthreads();
#pragma unroll
  for (int rep = 0; rep < 2; ++rep) {
    int idx = rep * 256 + tid;
    int d = idx >> 3;
    int toff = (idx & 7) * 8;
    BV8 o;
#pragma unroll
    for (int j = 0; j < 8; ++j) o.h[j] = vt[d][toff + j];
    *(short8*)(VTb + ((size_t)bh * 64 + d) * T_CTX + t0 + toff) = o.s;
  }
}

// ---------------- flash attention (causal), 32x32 MFMA, in-register softmax ----------------
// 2 waves x 32 q-rows (q-slab 64). KVBLK=64, double-buffered LDS staging.
// Swapped QK^T: S^T = mfma(A=K, B=Q^T) -> k axis lane-local (32 vals/lane, one q/lane-pair).
// All cross-lane traffic via __shfl_xor (compiler-visible; no inline asm feeding MFMA).
__global__ __launch_bounds__(128) void flash_attn(const __hip_bfloat16* __restrict__ Qb,
                                                  const __hip_bfloat16* __restrict__ Kb,
                                                  const __hip_bfloat16* __restrict__ VTb,
                                                  __hip_bfloat16* __restrict__ Y) {
  __shared__ __align__(16) char smem[32768];  // 2 bufs x (K 8KB + V 8KB)
  const int bh = blockIdx.x;
  const int b = bh >> 4, h = bh & 15;
  const int qi = 31 - (int)blockIdx.y;  // longest first
  const int q0 = qi * 64;
  const int tid = threadIdx.x;
  const int w = tid >> 6, l = tid & 63;
  const int l31 = l & 31, hh = l >> 5;
  const int sw7 = (l31 & 7) << 4;
  const int qw = q0 + w * 32;

  // Q as B-operand: lane q = qw + l31, contraction d = dblk*16 + hh*8 + j
  short8 qB[4];
#pragma unroll
  for (int dblk = 0; dblk < 4; ++dblk)
    qB[dblk] = *(const short8*)(Qb + ((size_t)bh * T_CTX + qw + l31) * 64 + dblk * 16 + hh * 8);

  f32x16 o0 = {}, o1 = {};  // O^T: d = dt*32 + (r&3) + 8*(r>>2) + 4*hh, q = l31
  float mrow = -1e30f, lrow = 0.0f;

  const int rowb = w * 8 + (l >> 3);  // 0..15
  const int colS = (l & 7) * 16;

  // prologue: stage tile 0 -> buf 0 (linear LDS dest, pre-swizzled global src)
#pragma unroll
  for (int rnd = 0; rnd < 4; ++rnd) {
    int row = rnd * 16 + rowb;
    int sw = colS ^ ((row & 7) << 4);
    GLD16((const char*)Kb + (((size_t)bh * T_CTX + row) << 7) + sw,
          smem + rnd * 2048 + w * 1024);
    GLD16((const char*)VTb + ((((size_t)bh * 64 + row) * T_CTX) << 1) + sw,
          smem + 8192 + rnd * 2048 + w * 1024);
  }

  int cur = 0;
  for (int t = 0; t <= qi; ++t) {
    const int kv0 = t << 6;
    __syncthreads();  // buf[cur] ready (vmcnt drained at barrier)
    if (t < qi) {
      const int nkv0 = (t + 1) << 6;
#pragma unroll
      for (int rnd = 0; rnd < 4; ++rnd) {
        int row = rnd * 16 + rowb;
        int sw = colS ^ ((row & 7) << 4);
        GLD16((const char*)Kb + (((size_t)bh * T_CTX + nkv0 + row) << 7) + sw,
              smem + (cur ^ 1) * 16384 + rnd * 2048 + w * 1024);
        GLD16((const char*)VTb + ((((size_t)bh * 64 + row) * T_CTX + nkv0) << 1) + sw,
              smem + (cur ^ 1) * 16384 + 8192 + rnd * 2048 + w * 1024);
      }
    }
    {
      const char* KsB = smem + cur * 16384;
      const char* VsB = KsB + 8192;

      // QK^T: sT0 k = kv0 + (r&3)+8*(r>>2)+4*hh, sT1 same +32; q = qw + l31
      f32x16 sT0 = {}, sT1 = {};
#pragma unroll
      for (int dblk = 0; dblk < 4; ++dblk) {
        int cb = dblk * 32 + hh * 16;
        short8 kA0 = *(const short8*)(KsB + l31 * 128 + (cb ^ sw7));
        short8 kA1 = *(const short8*)(KsB + (32 + l31) * 128 + (cb ^ sw7));
        __builtin_amdgcn_s_setprio(1);
        sT0 = __builtin_amdgcn_mfma_f32_32x32x16_bf16(kA0, qB[dblk], sT0, 0, 0, 0);
        sT1 = __builtin_amdgcn_mfma_f32_32x32x16_bf16(kA1, qB[dblk], sT1, 0, 0, 0);
        __builtin_amdgcn_s_setprio(0);
      }

      if (kv0 + 63 > qw) {  // diagonal tile: causal mask
        int q = qw + l31;
#pragma unroll
        for (int r = 0; r < 16; ++r) {
          int k0 = kv0 + 4 * hh + (r & 3) + 8 * (r >> 2);
          sT0[r] = (k0 > q) ? -1e30f : sT0[r];
          sT1[r] = (k0 + 32 > q) ? -1e30f : sT1[r];
        }
      }

      // --- in-register online softmax (exp2 domain; log2e folded into Q) ---
      float m8[8];
#pragma unroll
      for (int i = 0; i < 8; ++i)
        m8[i] = fmaxf(fmaxf(sT0[i], sT0[i + 8]), fmaxf(sT1[i], sT1[i + 8]));
      float ma = fmaxf(fmaxf(m8[0], m8[1]), fmaxf(m8[2], m8[3]));
      float mb = fmaxf(fmaxf(m8[4], m8[5]), fmaxf(m8[6], m8[7]));
      float mx = fmaxf(ma, mb);
      mx = fmaxf(mx, __shfl_xor(mx, 32));  // merge lane-pair halves (same q-row)
      if (!__all(mx - mrow <= 8.0f)) {     // defer-rescale (T13)
        float mnew = fmaxf(mrow, mx);
        float fac = __builtin_amdgcn_exp2f(mrow - mnew);
#pragma unroll
        for (int r = 0; r < 16; ++r) { o0[r] *= fac; o1[r] *= fac; }
        lrow *= fac;
        mrow = mnew;
      }
      float s8[8];
#pragma unroll
      for (int i = 0; i < 8; ++i) {
        sT0[i]     = __builtin_amdgcn_exp2f(sT0[i] - mrow);
        sT0[i + 8] = __builtin_amdgcn_exp2f(sT0[i + 8] - mrow);
        sT1[i]     = __builtin_amdgcn_exp2f(sT1[i] - mrow);
        sT1[i + 8] = __builtin_amdgcn_exp2f(sT1[i + 8] - mrow);
        s8[i] = (sT0[i] + sT0[i + 8]) + (sT1[i] + sT1[i + 8]);
      }
      float sa = (s8[0] + s8[1]) + (s8[2] + s8[3]);
      float sb = (s8[4] + s8[5]) + (s8[6] + s8[7]);
      float ps = sa + sb;
      ps += __shfl_xor(ps, 32);
      lrow += ps;

      // --- P -> bf16 pairs (IR pack) ---
      uint32_t wk0[8], wk1[8];
#pragma unroll
      for (int i = 0; i < 8; ++i) {
        wk0[i] = pkbf(sT0[2 * i], sT0[2 * i + 1]);
        wk1[i] = pkbf(sT1[2 * i], sT1[2 * i + 1]);
      }

      // PV: O^T[dt] += mfma(A=V^T, B=P^T), 4 k-slices of 16.
      // B-frag needs k = ks*16 + hh*8 + j; lane owns interleaved quads -> one
      // pre-selected __shfl_xor(32) pair per slice completes the fragment.
#pragma unroll
      for (int ks = 0; ks < 4; ++ks) {
        const uint32_t* wk = (ks < 2) ? wk0 : wk1;
        const int base = (ks & 1) * 4;
        uint32_t own0 = wk[base + 0], own1 = wk[base + 1];
        uint32_t own2 = wk[base + 2], own3 = wk[base + 3];
        uint32_t e0 = (uint32_t)__shfl_xor((int)(hh ? own0 : own2), 32);
        uint32_t e1 = (uint32_t)__shfl_xor((int)(hh ? own1 : own3), 32);
        U32x4 u;
        u.u[0] = hh ? e0 : own0;
        u.u[1] = hh ? e1 : own1;
        u.u[2] = hh ? own2 : e0;
        u.u[3] = hh ? own3 : e1;
        int cb = ks * 32 + hh * 16;
        short8 vA0 = *(const short8*)(VsB + l31 * 128 + (cb ^ sw7));
        short8 vA1 = *(const short8*)(VsB + (32 + l31) * 128 + (cb ^ sw7));
        __builtin_amdgcn_s_setprio(1);
        o0 = __builtin_amdgcn_mfma_f32_32x32x16_bf16(vA0, u.s8, o0, 0, 0, 0);
        o1 = __builtin_amdgcn_mfma_f32_32x32x16_bf16(vA1, u.s8, o1, 0, 0, 0);
        __builtin_amdgcn_s_setprio(0);
      }
    }
    cur ^= 1;
  }

  // epilogue: Y[b][q][h*64+d], d = dt*32 + 8*e + 4*hh + i
  float inv = 1.0f / lrow;
  size_t rowoff = ((size_t)(b * T_CTX + qw + l31)) * DIM_C + h * 64;
#pragma unroll
  for (int dt = 0; dt < 2; ++dt)
#pragma unroll
    for (int e = 0; e < 4; ++e) {
      union { ushort4 v; unsigned short us[4]; } st;
#pragma unroll
      for (int i = 0; i < 4; ++i) {
        union { __hip_bfloat16 h; unsigned short u; } cv;
        float val = (dt ? o1[e * 4 + i] : o0[e * 4 + i]) * inv;
        cv.h = __float2bfloat16(val);
        st.us[i] = cv.u;
      }
      *(ushort4*)(Y + rowoff + dt * 32 + 8 * e + 4 * hh) = st.v;
    }
}

// ---------------- launcher ----------------
extern "C" void kernel_launch(void* const* d_in, const int* in_sizes, int n_in,
                              void* d_out, int out_size, void* d_ws, size_t ws_size,
                              hipStream_t stream) {
  const float* x     = (const float*)d_in[0];
  const float* qkv_w = (const float*)d_in[1];
  const float* out_w = (const float*)d_in[2];
  float* out = (float*)d_out;

  char* ws = (char*)d_ws;
  const size_t MB = 1024 * 1024;
  __hip_bfloat16* xb    = (__hip_bfloat16*)(ws + 0 * MB);
  __hip_bfloat16* wqkvb = (__hip_bfloat16*)(ws + 8 * MB);
  __hip_bfloat16* woutb = (__hip_bfloat16*)(ws + 14 * MB);
  __hip_bfloat16* qkvb  = (__hip_bfloat16*)(ws + 16 * MB);
  __hip_bfloat16* Qb    = (__hip_bfloat16*)(ws + 40 * MB);
  __hip_bfloat16* Kb    = (__hip_bfloat16*)(ws + 48 * MB);
  __hip_bfloat16* VTb   = (__hip_bfloat16*)(ws + 56 * MB);
  __hip_bfloat16* yb    = (__hip_bfloat16*)(ws + 64 * MB);

  cvt_f32_bf16<<<4096, 256, 0, stream>>>(x, xb, 1048576);
  cvt_f32_bf16<<<3072, 256, 0, stream>>>(qkv_w, wqkvb, 786432);
  cvt_f32_bf16<<<1024, 256, 0, stream>>>(out_w, woutb, 262144);

  gemm_bt<__hip_bfloat16><<<dim3(24, 32), 256, 0, stream>>>(xb, wqkvb, qkvb, 4096, 3072, 1024);

  rope_pack<<<dim3(32, 32), 256, 0, stream>>>(qkvb, Qb, Kb, VTb);

  // 32 q-slabs of 64 rows x 32 bh = 1024 blocks, 2 waves each
  flash_attn<<<dim3(NBH, 32), 128, 0, stream>>>(Qb, Kb, VTb, yb);

  gemm_bt<float><<<dim3(8, 32), 256, 0, stream>>>(yb, woutb, out, 4096, 1024, 1024);
}